// Round 17
// baseline (1568.598 us; speedup 1.0000x reference)
//
#include <hip/hip_runtime.h>
#include <math.h>

#define TS 2048

typedef float f32x2 __attribute__((ext_vector_type(2)));
typedef _Float16 f16;
typedef _Float16 f16x2 __attribute__((ext_vector_type(2)));
typedef _Float16 f16x8 __attribute__((ext_vector_type(8)));

// f32-index LDS map (14016 f32 = 56.1 KB), 2 batches per block:
//  ldsx: f16 [2b][2buf][32][72] x chunks   xg0/xg1: f16 [2b][16][192]
//  h0h:  f16 [2b][32][64]  h1h: f16 [2b][16][64]   scro: f32 [2b][96]
#define XG0_B  4608
#define XG1_B  7680
#define H0H_B  10752
#define H1H_B  12800
#define SCRO_B 13824
#define LDSF   14016

// Superblock barrier: LDS-order only, no vmcnt drain (stage prefetch in flight)
#define BAR() do { asm volatile("s_waitcnt lgkmcnt(0)" ::: "memory"); __builtin_amdgcn_s_barrier(); } while(0)

union H8 { f16x8 v8; f16x2 v2[4]; };

__device__ __forceinline__ float sigmoidf_(float v){ return __builtin_amdgcn_rcpf(1.0f+__expf(-v)); }
__device__ __forceinline__ float tanhf_(float v){
  v = fminf(15.0f, fmaxf(-15.0f, v));
  const float e = __expf(2.0f*v);
  return (e-1.0f)*__builtin_amdgcn_rcpf(e+1.0f);
}
__device__ __forceinline__ float qadd1(float v){
  return v + __int_as_float(__builtin_amdgcn_update_dpp(0, __float_as_int(v), 0xB1, 0xF, 0xF, true));
}
__device__ __forceinline__ float wsum64(float v){
  v += __int_as_float(__builtin_amdgcn_update_dpp(0, __float_as_int(v), 0x111, 0xF, 0xF, true));
  v += __int_as_float(__builtin_amdgcn_update_dpp(0, __float_as_int(v), 0x112, 0xF, 0xF, true));
  v += __int_as_float(__builtin_amdgcn_update_dpp(0, __float_as_int(v), 0x114, 0xF, 0xF, true));
  v += __int_as_float(__builtin_amdgcn_update_dpp(0, __float_as_int(v), 0x118, 0xF, 0xF, true));
  v += __int_as_float(__builtin_amdgcn_update_dpp(0, __float_as_int(v), 0x142, 0xA, 0xF, true));
  v += __int_as_float(__builtin_amdgcn_update_dpp(0, __float_as_int(v), 0x143, 0xC, 0xF, true));
  return __int_as_float(__builtin_amdgcn_readlane(__float_as_int(v), 63));
}
__device__ __forceinline__ float fdot2_(f16x2 a, f16x2 b, float c){
  return __builtin_amdgcn_fdot2(a, b, c, false);
}
// 6 half-dots (rows {i2,i2+32} x 3 gates, 32-f16 half each): 96 fdot2
__device__ __forceinline__ void dot6(const f16* vec, const f16x2* Wp,
                                     float& a00, float& a01, float& a02,
                                     float& a10, float& a11, float& a12){
  H8 u[4];
  u[0].v8 = *(const f16x8*)(vec);
  u[1].v8 = *(const f16x8*)(vec+8);
  u[2].v8 = *(const f16x8*)(vec+16);
  u[3].v8 = *(const f16x8*)(vec+24);
  #pragma unroll
  for (int m=0;m<16;m++){
    const f16x2 hm = u[m>>2].v2[m&3];
    a00 = fdot2_(Wp[m],    hm, a00);
    a01 = fdot2_(Wp[16+m], hm, a01);
    a02 = fdot2_(Wp[32+m], hm, a02);
    a10 = fdot2_(Wp[48+m], hm, a10);
    a11 = fdot2_(Wp[64+m], hm, a11);
    a12 = fdot2_(Wp[80+m], hm, a12);
  }
}

// 7 waves = 448 threads, grid = 128 blocks, 2 batches per block (weights shared).
//  w0=L0 recurrence  w1=L1 recurrence (setprio 1)  w2=F1: xg1=W_ih1*h0+b
//  w3=F0: xg0=W_ih0*x+b  w4=x stager (32-step chunks)  w5=idle  w6=attn+pool
// Skews per interval k: L0@k, F1@k-1, L1@k-2, attn@k-3, F0@k+1.
// Each role processes batch A then batch B per step: B's issue hides A's latency.
// FIX vs R14: pair-reduce (qadd1) EACH accumulator BEFORE the p-select — the
// paired lanes hold partials of DIFFERENT rows (this one line was R14's failure).
__global__ __launch_bounds__(448, 1)
void gru_attn_fused(const float* __restrict__ x,
                    const float* __restrict__ w_ih0, const float* __restrict__ w_hh0,
                    const float* __restrict__ b_ih0, const float* __restrict__ b_hh0,
                    const float* __restrict__ w_ih1, const float* __restrict__ w_hh1,
                    const float* __restrict__ b_ih1, const float* __restrict__ b_hh1,
                    const float* __restrict__ attn_w1, const float* __restrict__ attn_b1,
                    const float* __restrict__ attn_w2, const float* __restrict__ attn_b2,
                    const float* __restrict__ ln_g, const float* __restrict__ ln_b,
                    const float* __restrict__ head_w1, const float* __restrict__ head_b1,
                    const float* __restrict__ head_w2, const float* __restrict__ head_b2,
                    float* __restrict__ out)
{
  __shared__ float lds[LDSF];
  f16* ldsx = (f16*)lds;               // [b][buf][32][72]
  f16* xg0h = (f16*)(lds + XG0_B);     // [b][16][192]
  f16* xg1h = (f16*)(lds + XG1_B);
  f16* h0h  = (f16*)(lds + H0H_B);     // [b][32][64]
  f16* h1h  = (f16*)(lds + H1H_B);     // [b][16][64]

  const int tid  = threadIdx.x;
  const int wid  = tid >> 6;
  const int lane = tid & 63;
  const int blkx = blockIdx.x;
  const int i2     = lane >> 1;
  const int p      = lane & 1;
  const int ownrow = i2 + 32*p;
  const int hoff   = p << 5;
  const size_t xstr = (size_t)64 * TS;
  const float* xb0 = x + (size_t)(2*blkx) * xstr;
  const float* xb1 = xb0 + xstr;

  f16x2 W[96];
  float4 SP[2][8];
  float bA=0.f,bB=0.f,bC=0.f,w2o=0.f,b2v=0.f;

  if (wid < 4) {
    const float* wsrc = (wid==0)? w_hh0 : (wid==1)? w_hh1 : (wid==2)? w_ih1 : w_ih0;
    for (int r2=0;r2<2;r2++)
      for (int g=0;g<3;g++)
        for (int m=0;m<16;m++){
          const f32x2 v = *(const f32x2*)(wsrc + (size_t)(g*64 + i2 + 32*r2)*64 + hoff + 2*m);
          W[(r2*3+g)*16+m] = (f16x2){(f16)v.x,(f16)v.y};
        }
    for (int q2=0;q2<96;q2++) asm volatile("" : "+v"(W[q2]));
    const float* bsrc = (wid==0)? b_hh0 : (wid==1)? b_hh1 : (wid==2)? b_ih1 : b_ih0;
    bA = bsrc[ownrow]; bB = bsrc[64+ownrow]; bC = bsrc[128+ownrow];
  } else if (wid == 6) {
    for (int r2=0;r2<2;r2++)
      for (int m=0;m<16;m++){
        const f32x2 v = *(const f32x2*)(attn_w1 + (size_t)(i2+32*r2)*64 + hoff + 2*m);
        W[r2*16+m] = (f16x2){(f16)v.x,(f16)v.y};
      }
    for (int q2=0;q2<32;q2++) asm volatile("" : "+v"(W[q2]));
    bA = attn_b1[ownrow]; w2o = attn_w2[ownrow]; b2v = attn_b2[0];
  }

  // prologue: zero h rings (3072 u32, contiguous), stage x chunk 0 for both batches
  for (int idx = tid; idx < 3072; idx += 448) ((uint32_t*)(lds + H0H_B))[idx] = 0u;
  if (wid == 4) {
    #pragma unroll
    for (int be=0;be<2;be++){
      const float* src = (be ? xb1 : xb0) + (size_t)lane*TS;
      #pragma unroll
      for (int q=0;q<8;q++) SP[be][q] = *(const float4*)(src + 4*q);
    }
    #pragma unroll
    for (int be=0;be<2;be++){
      f16* dst = ldsx + be*4608;
      #pragma unroll
      for (int q=0;q<8;q++){
        dst[(4*q+0)*72 + lane] = (f16)SP[be][q].x;
        dst[(4*q+1)*72 + lane] = (f16)SP[be][q].y;
        dst[(4*q+2)*72 + lane] = (f16)SP[be][q].z;
        dst[(4*q+3)*72 + lane] = (f16)SP[be][q].w;
      }
    }
  }
  __syncthreads();

  if (wid <= 1) __builtin_amdgcn_s_setprio(1);

  float hreg0=0.f, hreg1=0.f;                       // L-waves: per-batch h master
  float am0=-1e30f, aZ0=0.f, aP0=0.f;               // attn pooling, batch 0
  float am1=-1e30f, aZ1=0.f, aP1=0.f;               // batch 1

  #pragma unroll 1
  for (int k = -1; k <= 258; ++k) {
    if (wid <= 1) {
      const int blkk = k - (wid << 1);
      if (0 <= blkk && blkk < 256) {
        f16* hring = wid ? h1h : h0h;
        f16* xgc   = wid ? xg1h : xg0h;
        const int emask = wid ? 1023 : 2047;        // f16-elem ring mask
        const int bstr  = wid ? 1024 : 2048;        // per-batch ring stride
        #pragma unroll
        for (int j=0;j<8;j++){
          const int t = (blkk<<3) + j;
          #pragma unroll
          for (int be=0;be<2;be++){
            const int xi = be*3072 + (t&15)*192;
            const float xgr = (float)xgc[xi + ownrow];
            const float xgz = (float)xgc[xi + 64 + ownrow];
            const float xgn = (float)xgc[xi + 128 + ownrow];
            const f16* hv = hring + be*bstr + (((t-1)<<6) & emask) + hoff;
            float a00=0,a01=0,a02=0,a10=0,a11=0,a12=0;
            dot6(hv, W, a00,a01,a02,a10,a11,a12);
            a00=qadd1(a00); a01=qadd1(a01); a02=qadd1(a02);  // reduce EACH,
            a10=qadd1(a10); a11=qadd1(a11); a12=qadd1(a12);  // THEN select
            const float hr = p ? a10 : a00;
            const float hz = p ? a11 : a01;
            const float hn = p ? a12 : a02;
            const float r = sigmoidf_(xgr + hr + bA);
            const float z = sigmoidf_(xgz + hz + bB);
            const float n = tanhf_(xgn + r*(hn + bC));
            float h = be ? hreg1 : hreg0;
            h = n + z*(h - n);
            if (be) hreg1 = h; else hreg0 = h;
            hring[be*bstr + ((t<<6) & emask) + ownrow] = (f16)h;
          }
        }
      }
    } else if (wid <= 3) {
      const int blkk = (wid==2) ? k-1 : k+1;
      if (0 <= blkk && blkk < 256) {
        f16* xgw = (wid==2) ? xg1h : xg0h;
        #pragma unroll
        for (int j=0;j<8;j++){
          const int t = (blkk<<3) + j;
          #pragma unroll
          for (int be=0;be<2;be++){
            const f16* vec;
            if (wid==2) vec = h0h + be*2048 + (((t-1)<<6) & 2047) + hoff;
            else        vec = ldsx + be*4608 + ((t>>5)&1)*2304 + (t&31)*72 + hoff;
            float a00=0,a01=0,a02=0,a10=0,a11=0,a12=0;
            dot6(vec, W, a00,a01,a02,a10,a11,a12);
            a00=qadd1(a00); a01=qadd1(a01); a02=qadd1(a02);  // reduce EACH,
            a10=qadd1(a10); a11=qadd1(a11); a12=qadd1(a12);  // THEN select
            const float gr = (p ? a10 : a00) + bA;
            const float gz = (p ? a11 : a01) + bB;
            const float gn = (p ? a12 : a02) + bC;
            const int xi = be*3072 + (t&15)*192;
            xgw[xi + ownrow]       = (f16)gr;
            xgw[xi + 64 + ownrow]  = (f16)gz;
            xgw[xi + 128 + ownrow] = (f16)gn;
          }
        }
      }
    } else if (wid == 4) {
      const int kk = k + 1, ph = kk & 3, Q = (kk >> 2) + 1;
      if (Q <= 63) {
        if (ph == 1) {
          #pragma unroll
          for (int be=0;be<2;be++){
            const float* src = (be ? xb1 : xb0) + (size_t)lane*TS + Q*32;
            #pragma unroll
            for (int q=0;q<8;q++) SP[be][q] = *(const float4*)(src + 4*q);
          }
        } else if (ph == 3) {
          #pragma unroll
          for (int be=0;be<2;be++){
            f16* dst = ldsx + be*4608 + (Q&1)*2304;
            #pragma unroll
            for (int q=0;q<8;q++){
              dst[(4*q+0)*72 + lane] = (f16)SP[be][q].x;
              dst[(4*q+1)*72 + lane] = (f16)SP[be][q].y;
              dst[(4*q+2)*72 + lane] = (f16)SP[be][q].z;
              dst[(4*q+3)*72 + lane] = (f16)SP[be][q].w;
            }
          }
        }
      }
    } else if (wid == 6) {
      const int blkk = k - 3;
      if (0 <= blkk && blkk < 256) {
        #pragma unroll
        for (int j=0;j<8;j++){
          const int t = (blkk<<3) + j;
          #pragma unroll
          for (int be=0;be<2;be++){
            const f16* hv = h1h + be*1024 + ((t&15)<<6) + hoff;
            H8 u[4];
            u[0].v8 = *(const f16x8*)(hv);
            u[1].v8 = *(const f16x8*)(hv+8);
            u[2].v8 = *(const f16x8*)(hv+16);
            u[3].v8 = *(const f16x8*)(hv+24);
            float a0=0.f, a1=0.f;
            #pragma unroll
            for (int m=0;m<16;m++){
              const f16x2 hm = u[m>>2].v2[m&3];
              a0 = fdot2_(W[m],    hm, a0);
              a1 = fdot2_(W[16+m], hm, a1);
            }
            a0 = qadd1(a0); a1 = qadd1(a1);                 // reduce EACH, then select
            const float a  = tanhf_((p ? a1 : a0) + bA);
            const float s  = wsum64(w2o * a) + b2v;
            const float hc = (float)h1h[be*1024 + ((t&15)<<6) + lane];
            const float mo = be ? am1 : am0;
            const float mn = fmaxf(mo, s);
            const float sc = __expf(mo - mn);
            const float pp = __expf(s - mn);
            if (be) { aZ1 = aZ1*sc + pp; aP1 = aP1*sc + pp*hc; am1 = mn; }
            else    { aZ0 = aZ0*sc + pp; aP0 = aP0*sc + pp*hc; am0 = mn; }
          }
        }
      }
    }
    BAR();
  }

  // ---------------- epilogue (both batches) ----------------
  if (wid == 6) {
    #pragma unroll
    for (int be=0;be<2;be++){
      const float pooled = (be ? aP1/aZ1 : aP0/aZ0);
      float mu = pooled;
      #pragma unroll
      for (int m=1;m<64;m<<=1) mu += __shfl_xor(mu, m, 64);
      mu *= (1.0f/64.0f);
      const float d = pooled - mu;
      float var = d*d;
      #pragma unroll
      for (int m=1;m<64;m<<=1) var += __shfl_xor(var, m, 64);
      var *= (1.0f/64.0f);
      const float y = d * rsqrtf(var + 1e-5f) * ln_g[lane] + ln_b[lane];
      lds[SCRO_B + be*96 + lane] = y;
    }
  }
  __syncthreads();
  if (wid <= 1 && lane < 32) {
    const int be = wid;
    const float* hw = head_w1 + lane*64;
    float acc = head_b1[lane];
    #pragma unroll
    for (int kq=0;kq<16;kq++){
      const float4 w4 = ((const float4*)hw)[kq];
      acc += w4.x*lds[SCRO_B+be*96+4*kq+0] + w4.y*lds[SCRO_B+be*96+4*kq+1]
           + w4.z*lds[SCRO_B+be*96+4*kq+2] + w4.w*lds[SCRO_B+be*96+4*kq+3];
    }
    const float u = 0.5f*acc*(1.0f + erff(acc*0.70710678118654752f)); // exact GELU
    lds[SCRO_B + be*96 + 64 + lane] = u;
  }
  __syncthreads();
  if (wid <= 1 && lane < 8) {
    const int be = wid;
    const float* hw = head_w2 + lane*32;
    float acc = head_b2[lane];
    #pragma unroll
    for (int kq=0;kq<8;kq++){
      const float4 w4 = ((const float4*)hw)[kq];
      acc += w4.x*lds[SCRO_B+be*96+64+4*kq+0] + w4.y*lds[SCRO_B+be*96+64+4*kq+1]
           + w4.z*lds[SCRO_B+be*96+64+4*kq+2] + w4.w*lds[SCRO_B+be*96+64+4*kq+3];
    }
    out[(size_t)(2*blkx + be)*8 + lane] = acc;
  }
}

extern "C" void kernel_launch(void* const* d_in, const int* in_sizes, int n_in,
                              void* d_out, int out_size, void* d_ws, size_t ws_size,
                              hipStream_t stream) {
  (void)in_sizes; (void)n_in; (void)d_ws; (void)ws_size; (void)out_size;
  const float* x       = (const float*)d_in[0];
  const float* w_ih0   = (const float*)d_in[1];
  const float* w_hh0   = (const float*)d_in[2];
  const float* b_ih0   = (const float*)d_in[3];
  const float* b_hh0   = (const float*)d_in[4];
  const float* w_ih1   = (const float*)d_in[5];
  const float* w_hh1   = (const float*)d_in[6];
  const float* b_ih1   = (const float*)d_in[7];
  const float* b_hh1   = (const float*)d_in[8];
  const float* attn_w1 = (const float*)d_in[9];
  const float* attn_b1 = (const float*)d_in[10];
  const float* attn_w2 = (const float*)d_in[11];
  const float* attn_b2 = (const float*)d_in[12];
  const float* ln_g    = (const float*)d_in[13];
  const float* ln_b    = (const float*)d_in[14];
  const float* head_w1 = (const float*)d_in[15];
  const float* head_b1 = (const float*)d_in[16];
  const float* head_w2 = (const float*)d_in[17];
  const float* head_b2 = (const float*)d_in[18];
  hipLaunchKernelGGL(gru_attn_fused, dim3(128), dim3(448), 0, stream,
                     x, w_ih0, w_hh0, b_ih0, b_hh0, w_ih1, w_hh1, b_ih1, b_hh1,
                     attn_w1, attn_b1, attn_w2, attn_b2, ln_g, ln_b,
                     head_w1, head_b1, head_w2, head_b2, (float*)d_out);
}

// Round 18
// 1353.539 us; speedup vs baseline: 1.1589x; 1.1589x over previous
//
#include <hip/hip_runtime.h>
#include <math.h>

#define TS 2048
#define PB 13920   // per-batch LDS stride (f32)

typedef float f32x2 __attribute__((ext_vector_type(2)));
typedef _Float16 f16;
typedef _Float16 f16x2 __attribute__((ext_vector_type(2)));
typedef _Float16 f16x8 __attribute__((ext_vector_type(8)));

// per-batch LDS float-index map (R12-identical)
#define XG0_B  5120
#define XG1_B  8192
#define H0H_B  11264
#define H1H_B  12288
#define H1F_B  12800
#define SCRO_B 13824

#define BAR() do { asm volatile("s_waitcnt lgkmcnt(0)" ::: "memory"); __builtin_amdgcn_s_barrier(); } while(0)
#define FEN() asm volatile("s_waitcnt lgkmcnt(0)" ::: "memory")

union H8 { f16x8 v8; f16x2 v2[4]; };

__device__ __forceinline__ float sigmoidf_(float v){ return __builtin_amdgcn_rcpf(1.0f+__expf(-v)); }
__device__ __forceinline__ float tanhf_(float v){
  v = fminf(15.0f, fmaxf(-15.0f, v));
  const float e = __expf(2.0f*v);
  return (e-1.0f)*__builtin_amdgcn_rcpf(e+1.0f);
}
__device__ __forceinline__ float qadd1(float v){
  return v + __int_as_float(__builtin_amdgcn_update_dpp(0, __float_as_int(v), 0xB1, 0xF, 0xF, true));
}
__device__ __forceinline__ float wsum64(float v){
  v += __int_as_float(__builtin_amdgcn_update_dpp(0, __float_as_int(v), 0x111, 0xF, 0xF, true));
  v += __int_as_float(__builtin_amdgcn_update_dpp(0, __float_as_int(v), 0x112, 0xF, 0xF, true));
  v += __int_as_float(__builtin_amdgcn_update_dpp(0, __float_as_int(v), 0x114, 0xF, 0xF, true));
  v += __int_as_float(__builtin_amdgcn_update_dpp(0, __float_as_int(v), 0x118, 0xF, 0xF, true));
  v += __int_as_float(__builtin_amdgcn_update_dpp(0, __float_as_int(v), 0x142, 0xA, 0xF, true));
  v += __int_as_float(__builtin_amdgcn_update_dpp(0, __float_as_int(v), 0x143, 0xC, 0xF, true));
  return __int_as_float(__builtin_amdgcn_readlane(__float_as_int(v), 63));
}
__device__ __forceinline__ float fdot2_(f16x2 a, f16x2 b, float c){
  return __builtin_amdgcn_fdot2(a, b, c, false);
}
// 6 half-dots (rows {i2,i2+32} x 3 gates, 32-f16 half each): 96 fdot2
__device__ __forceinline__ void dot6(const f16* vec, const f16x2* Wp,
                                     float& a00, float& a01, float& a02,
                                     float& a10, float& a11, float& a12){
  H8 u[4];
  u[0].v8 = *(const f16x8*)(vec);
  u[1].v8 = *(const f16x8*)(vec+8);
  u[2].v8 = *(const f16x8*)(vec+16);
  u[3].v8 = *(const f16x8*)(vec+24);
  #pragma unroll
  for (int m=0;m<16;m++){
    const f16x2 hm = u[m>>2].v2[m&3];
    a00 = fdot2_(Wp[m],    hm, a00);
    a01 = fdot2_(Wp[16+m], hm, a01);
    a02 = fdot2_(Wp[32+m], hm, a02);
    a10 = fdot2_(Wp[48+m], hm, a10);
    a11 = fdot2_(Wp[64+m], hm, a11);
    a12 = fdot2_(Wp[80+m], hm, a12);
  }
}

// 12 waves = 768 threads, grid = 128 blocks, 2 batches per block.
// Batch A = waves 0-5 {L0,L1,F1,F0,stage,attn}; batch B = waves 6-11 (same).
// SIMD (wid&3) carries one critical L-wave + one feeder + one light wave from
// the OTHER batch -> TLP hides the recurrence chain's FEN/LDS latency.
// Per-batch dataflow, rings, skews = R16 (proven): SBs of 8 steps, 1 BAR/SB.
__global__ __launch_bounds__(768, 1)
void gru_attn_fused(const float* __restrict__ x,
                    const float* __restrict__ w_ih0, const float* __restrict__ w_hh0,
                    const float* __restrict__ b_ih0, const float* __restrict__ b_hh0,
                    const float* __restrict__ w_ih1, const float* __restrict__ w_hh1,
                    const float* __restrict__ b_ih1, const float* __restrict__ b_hh1,
                    const float* __restrict__ attn_w1, const float* __restrict__ attn_b1,
                    const float* __restrict__ attn_w2, const float* __restrict__ attn_b2,
                    const float* __restrict__ ln_g, const float* __restrict__ ln_b,
                    const float* __restrict__ head_w1, const float* __restrict__ head_b1,
                    const float* __restrict__ head_w2, const float* __restrict__ head_b2,
                    float* __restrict__ out)
{
  __shared__ float lds[2*PB];
  const int tid  = threadIdx.x;
  const int wid  = tid >> 6;
  const int lane = tid & 63;
  const int blkx = blockIdx.x;
  const int be   = (wid >= 6);          // batch within block
  const int rl   = be ? wid-6 : wid;    // role 0..5

  float* ldsb = lds + be*PB;
  f16*   ldsx = (f16*)ldsb;
  float* xg0  = ldsb + XG0_B;
  float* xg1  = ldsb + XG1_B;
  f16*   h0h  = (f16*)(ldsb + H0H_B);
  f16*   h1h  = (f16*)(ldsb + H1H_B);
  float* h1f  = ldsb + H1F_B;

  const int i2     = lane >> 1;
  const int p      = lane & 1;
  const int ownrow = i2 + 32*p;
  const int hoff   = p << 5;
  const float* xb  = x + (size_t)(2*blkx + be) * 64 * TS;

  f16x2 W[96];
  float4 SP[16];
  float bA=0.f,bB=0.f,bC=0.f,w2o=0.f,b2v=0.f;

  if (rl < 4) {
    const float* wsrc = (rl==0)? w_hh0 : (rl==1)? w_hh1 : (rl==2)? w_ih1 : w_ih0;
    for (int r2=0;r2<2;r2++)
      for (int g=0;g<3;g++)
        for (int m=0;m<16;m++){
          const f32x2 v = *(const f32x2*)(wsrc + (size_t)(g*64 + i2 + 32*r2)*64 + hoff + 2*m);
          W[(r2*3+g)*16+m] = (f16x2){(f16)v.x,(f16)v.y};
        }
    for (int q2=0;q2<96;q2++) asm volatile("" : "+v"(W[q2]));
    const float* bsrc = (rl==0)? b_hh0 : (rl==1)? b_hh1 : (rl==2)? b_ih1 : b_ih0;
    bA = bsrc[ownrow]; bB = bsrc[64+ownrow]; bC = bsrc[128+ownrow];
  } else if (rl == 5) {
    for (int r2=0;r2<2;r2++)
      for (int m=0;m<16;m++){
        const f32x2 v = *(const f32x2*)(attn_w1 + (size_t)(i2+32*r2)*64 + hoff + 2*m);
        W[r2*16+m] = (f16x2){(f16)v.x,(f16)v.y};
      }
    for (int q2=0;q2<32;q2++) asm volatile("" : "+v"(W[q2]));
    bA = attn_b1[ownrow]; w2o = attn_w2[ownrow]; b2v = attn_b2[0];
  }

  // prologue: zero both batches' h rings (1536 u32 each, contiguous h0h+h1h)
  for (int idx = tid; idx < 1536; idx += 768) ((uint32_t*)(lds + H0H_B))[idx] = 0u;
  for (int idx = tid; idx < 1536; idx += 768) ((uint32_t*)(lds + PB + H0H_B))[idx] = 0u;
  if (rl == 4) {   // stage x tile 0 for own batch
    const float* src = xb + (size_t)lane*TS;
    #pragma unroll
    for (int kq=0;kq<16;kq++) SP[kq] = *(const float4*)(src + 4*kq);
    #pragma unroll
    for (int kq=0;kq<16;kq++){
      ldsx[(4*kq+0)*80 + lane] = (f16)SP[kq].x;
      ldsx[(4*kq+1)*80 + lane] = (f16)SP[kq].y;
      ldsx[(4*kq+2)*80 + lane] = (f16)SP[kq].z;
      ldsx[(4*kq+3)*80 + lane] = (f16)SP[kq].w;
    }
  }
  __syncthreads();

  if (rl <= 1) __builtin_amdgcn_s_setprio(1);

  float hreg = 0.f;
  float am = -1e30f, aZ = 0.f, aP = 0.f;

  #pragma unroll 1
  for (int k = -1; k <= 258; ++k) {
    if (rl <= 1) {
      const int blk = k - (rl << 1);
      if (0 <= blk && blk < 256) {
        f16*   hring = rl ? h1h : h0h;
        float* xgc   = rl ? xg1 : xg0;
        const int emask = rl ? 1023 : 2047;
        const int t0 = blk << 3;
        float xgr = xgc[(t0&15)*192 + ownrow];
        float xgz = xgc[(t0&15)*192 + 64 + ownrow];
        float xgn = xgc[(t0&15)*192 + 128 + ownrow];
        #pragma unroll
        for (int j=0;j<8;j++){
          const int t = t0 + j;
          FEN();                                            // drain h write(t-1) + xg reads
          const f16* hv = hring + (((t-1)<<6) & emask) + hoff;
          float a00=0,a01=0,a02=0,a10=0,a11=0,a12=0;
          dot6(hv, W, a00,a01,a02,a10,a11,a12);
          a00=qadd1(a00); a01=qadd1(a01); a02=qadd1(a02);   // reduce EACH, then select
          a10=qadd1(a10); a11=qadd1(a11); a12=qadd1(a12);
          const float hr = p ? a10 : a00;
          const float hz = p ? a11 : a01;
          const float hn = p ? a12 : a02;
          const float r = sigmoidf_(xgr + hr + bA);
          const float z = sigmoidf_(xgz + hz + bB);
          const float n = tanhf_(xgn + r*(hn + bC));
          hreg = n + z*(hreg - n);
          hring[((t<<6) & emask) + ownrow] = (f16)hreg;
          if (rl) h1f[((t&15)<<6) + ownrow] = hreg;
          if (j < 7) {                                      // prefetch xg(t+1), same SB
            const int xi = ((t+1)&15)*192;
            xgr = xgc[xi + ownrow];
            xgz = xgc[xi + 64 + ownrow];
            xgn = xgc[xi + 128 + ownrow];
          }
        }
      }
    } else if (rl <= 3) {
      const int blk = (rl==2) ? k-1 : k+1;
      if (0 <= blk && blk < 256) {
        float* xgw = (rl==2) ? xg1 : xg0;
        #pragma unroll
        for (int j=0;j<8;j++){
          const int t = (blk<<3) + j;
          const f16* vec;
          if (rl==2) vec = h0h + (((t-1)<<6) & 2047) + hoff;
          else       vec = ldsx + ((t>>6)&1)*5120 + (t&63)*80 + hoff;
          float a00=0,a01=0,a02=0,a10=0,a11=0,a12=0;
          dot6(vec, W, a00,a01,a02,a10,a11,a12);
          a00=qadd1(a00); a01=qadd1(a01); a02=qadd1(a02);   // reduce EACH, then select
          a10=qadd1(a10); a11=qadd1(a11); a12=qadd1(a12);
          const int xi = (t & 15) * 192;
          xgw[xi + ownrow]       = (p ? a10 : a00) + bA;
          xgw[xi + 64 + ownrow]  = (p ? a11 : a01) + bB;
          xgw[xi + 128 + ownrow] = (p ? a12 : a02) + bC;
        }
      }
    } else if (rl == 4) {
      const int kk = k + 1, tile = kk >> 3, ph = kk & 7;
      if (ph == 1 && tile < 31) {
        const float* src = xb + (size_t)lane*TS + (tile+1)*64;
        #pragma unroll
        for (int kq=0;kq<16;kq++) SP[kq] = *(const float4*)(src + 4*kq);
      } else if (ph == 5 && tile < 31) {
        f16* dsth = ldsx + ((tile+1)&1)*5120;
        #pragma unroll
        for (int kq=0;kq<16;kq++){
          dsth[(4*kq+0)*80 + lane] = (f16)SP[kq].x;
          dsth[(4*kq+1)*80 + lane] = (f16)SP[kq].y;
          dsth[(4*kq+2)*80 + lane] = (f16)SP[kq].z;
          dsth[(4*kq+3)*80 + lane] = (f16)SP[kq].w;
        }
      }
    } else {  // rl == 5: attention + online-softmax pooling @ block k-3
      const int blk = k - 3;
      if (0 <= blk && blk < 256) {
        #pragma unroll
        for (int j=0;j<8;j++){
          const int t = (blk<<3) + j;
          const f16* hv = h1h + ((t&15)<<6) + hoff;
          H8 u[4];
          u[0].v8 = *(const f16x8*)(hv);
          u[1].v8 = *(const f16x8*)(hv+8);
          u[2].v8 = *(const f16x8*)(hv+16);
          u[3].v8 = *(const f16x8*)(hv+24);
          float a0=0.f, a1=0.f;
          #pragma unroll
          for (int m=0;m<16;m++){
            const f16x2 hm = u[m>>2].v2[m&3];
            a0 = fdot2_(W[m],    hm, a0);
            a1 = fdot2_(W[16+m], hm, a1);
          }
          a0 = qadd1(a0); a1 = qadd1(a1);                   // reduce EACH, then select
          const float a  = tanhf_((p ? a1 : a0) + bA);
          const float s  = wsum64(w2o * a) + b2v;
          const float hc = h1f[((t&15)<<6) + lane];
          const float mn = fmaxf(am, s);
          const float sc = __expf(am - mn);
          const float pp = __expf(s - mn);
          aZ = aZ*sc + pp;
          aP = aP*sc + pp*hc;
          am = mn;
        }
      }
    }
    BAR();
  }

  // ---------------- epilogue (per batch) ----------------
  if (rl == 5) {
    const float pooled = aP / aZ;
    float mu = pooled;
    #pragma unroll
    for (int m=1;m<64;m<<=1) mu += __shfl_xor(mu, m, 64);
    mu *= (1.0f/64.0f);
    const float d = pooled - mu;
    float var = d*d;
    #pragma unroll
    for (int m=1;m<64;m<<=1) var += __shfl_xor(var, m, 64);
    var *= (1.0f/64.0f);
    const float y = d * rsqrtf(var + 1e-5f) * ln_g[lane] + ln_b[lane];
    ldsb[SCRO_B + lane] = y;
  }
  __syncthreads();
  if (rl == 0 && lane < 32) {
    const float* hw = head_w1 + lane*64;
    float acc = head_b1[lane];
    #pragma unroll
    for (int kq=0;kq<16;kq++){
      const float4 w4 = ((const float4*)hw)[kq];
      acc += w4.x*ldsb[SCRO_B+4*kq+0] + w4.y*ldsb[SCRO_B+4*kq+1]
           + w4.z*ldsb[SCRO_B+4*kq+2] + w4.w*ldsb[SCRO_B+4*kq+3];
    }
    const float u = 0.5f*acc*(1.0f + erff(acc*0.70710678118654752f)); // exact GELU
    ldsb[SCRO_B + 64 + lane] = u;
  }
  __syncthreads();
  if (rl == 0 && lane < 8) {
    const float* hw = head_w2 + lane*32;
    float acc = head_b2[lane];
    #pragma unroll
    for (int kq=0;kq<8;kq++){
      const float4 w4 = ((const float4*)hw)[kq];
      acc += w4.x*ldsb[SCRO_B+64+4*kq+0] + w4.y*ldsb[SCRO_B+64+4*kq+1]
           + w4.z*ldsb[SCRO_B+64+4*kq+2] + w4.w*ldsb[SCRO_B+64+4*kq+3];
    }
    out[(size_t)(2*blkx + be)*8 + lane] = acc;
  }
}

extern "C" void kernel_launch(void* const* d_in, const int* in_sizes, int n_in,
                              void* d_out, int out_size, void* d_ws, size_t ws_size,
                              hipStream_t stream) {
  (void)in_sizes; (void)n_in; (void)d_ws; (void)ws_size; (void)out_size;
  const float* x       = (const float*)d_in[0];
  const float* w_ih0   = (const float*)d_in[1];
  const float* w_hh0   = (const float*)d_in[2];
  const float* b_ih0   = (const float*)d_in[3];
  const float* b_hh0   = (const float*)d_in[4];
  const float* w_ih1   = (const float*)d_in[5];
  const float* w_hh1   = (const float*)d_in[6];
  const float* b_ih1   = (const float*)d_in[7];
  const float* b_hh1   = (const float*)d_in[8];
  const float* attn_w1 = (const float*)d_in[9];
  const float* attn_b1 = (const float*)d_in[10];
  const float* attn_w2 = (const float*)d_in[11];
  const float* attn_b2 = (const float*)d_in[12];
  const float* ln_g    = (const float*)d_in[13];
  const float* ln_b    = (const float*)d_in[14];
  const float* head_w1 = (const float*)d_in[15];
  const float* head_b1 = (const float*)d_in[16];
  const float* head_w2 = (const float*)d_in[17];
  const float* head_b2 = (const float*)d_in[18];
  hipLaunchKernelGGL(gru_attn_fused, dim3(128), dim3(768), 0, stream,
                     x, w_ih0, w_hh0, b_ih0, b_hh0, w_ih1, w_hh1, b_ih1, b_hh1,
                     attn_w1, attn_b1, attn_w2, attn_b2, ln_g, ln_b,
                     head_w1, head_b1, head_w2, head_b2, (float*)d_out);
}